// Round 2
// baseline (225.449 us; speedup 1.0000x reference)
//
#include <hip/hip_runtime.h>

// Attention_msa_TwoStream. Only v_cls (d_in[1]) feeds the outputs; the
// qkv-MLP / q / k / softmax(qk) are dead code in the reference.
// N=3200, H=8, d=64, C=512. All I/O fp32 (threshold arithmetic confirms:
// out0 thr = 2% of max|ref|, no bf16 floor). Internals use bf16 MFMA.
// Outputs: x_out (3200x1024 f32) ++ sim_round2 (3200x3200 f32).

#define NN 3200
#define HEADS 8
#define DH 64
#define CC 512          // HEADS*DH
#define BN 32           // rows per block in main kernel
#define BM 32           // m-chunk
#define NSPLIT 4
#define MSPL (NN / NSPLIT)   // 800
#define CHUNKS (MSPL / BM)   // 25
#define ROWBLKS (NN / BN)    // 100

typedef __attribute__((ext_vector_type(8))) short short8;   // 8 bf16 (4 VGPRs)
typedef __attribute__((ext_vector_type(4))) float f32x4;

static __device__ __forceinline__ unsigned short f2b(float f) {
  union { float f; unsigned u; } x; x.f = f;
  unsigned u = x.u;
  unsigned r = u + 0x7FFFu + ((u >> 16) & 1u);   // RTN-even
  return (unsigned short)(r >> 16);
}

// ---------------------------------------------------------------------------
// Kernel 1: per-(n,h) L2 norm of v (fp32 in); write vn head-major [h][n][64]
// as bf16, and the x_ori half of the output: out[n][512+c] = v[n][c] (f32).
__global__ void k_norm(const float* __restrict__ v,
                       unsigned short* __restrict__ vn,
                       float* __restrict__ out) {
  int gw   = (int)((blockIdx.x * blockDim.x + threadIdx.x) >> 6);
  int lane = threadIdx.x & 63;
  int n = gw >> 3, h = gw & 7;
  float val = v[(size_t)n * CC + h * DH + lane];
  float ss = val * val;
  #pragma unroll
  for (int off = 32; off >= 1; off >>= 1) ss += __shfl_xor(ss, off, 64);
  float inv = 1.0f / (sqrtf(ss) + 1e-8f);
  vn[((size_t)h * NN + n) * DH + lane] = f2b(val * inv);
  out[(size_t)n * (2 * CC) + CC + h * DH + lane] = val;
}

// ---------------------------------------------------------------------------
// Kernel 1b: vT[h][j][n] = bf16(v[n][h*64+j])  (transposed per head; B operand
// of the second GEMM). LDS-tiled 64x64 so both global phases are coalesced.
__global__ void k_transpose(const float* __restrict__ v,
                            unsigned short* __restrict__ vT) {
  __shared__ unsigned short tile[DH][73];   // odd-ish stride vs 32 banks
  int h  = blockIdx.x & 7;
  int n0 = (int)(blockIdx.x >> 3) * 64;
  int t = threadIdx.x;
  {
    int j = t & 63, rb = (t >> 6) * 16;
    #pragma unroll
    for (int i = 0; i < 16; i++) {
      int r = rb + i;
      tile[j][r] = f2b(v[(size_t)(n0 + r) * CC + h * DH + j]);
    }
  }
  __syncthreads();
  {
    int r = t & 63, jb = (t >> 6) * 16;
    #pragma unroll
    for (int i = 0; i < 16; i++) {
      int jj = jb + i;
      vT[((size_t)h * DH + jj) * NN + n0 + r] = tile[jj][r];
    }
  }
}

// ---------------------------------------------------------------------------
// Kernel 2: fused main. Block = 512 thr = 8 waves = 8 heads; owns BN=32 rows,
// iterates one of NSPLIT m-ranges in BM=32 chunks.
//  per chunk:  Gram MFMA (S_h, 16x16x32 bf16) -> LDS
//              -> head reduction: R=mean_h S, write R, accumulate Z / Esel
//              -> rebuild S' = S*blockmask as bf16 A-frags, MFMA X += S' * V
__global__ __launch_bounds__(512) void k_main(const unsigned short* __restrict__ vn,
                                              const unsigned short* __restrict__ vT,
                                              float* __restrict__ Rg,
                                              float* __restrict__ Xacc,
                                              float* __restrict__ Zg,
                                              float* __restrict__ Eg) {
  __shared__ __align__(16) float Ssc[HEADS][BN][33];   // +1 pad vs 32 banks
  int tid  = threadIdx.x;
  int h    = tid >> 6;
  int lane = tid & 63;
  int quad = lane >> 4, l16 = lane & 15;
  int blockrow = (int)blockIdx.x % ROWBLKS;
  int split    = (int)blockIdx.x / ROWBLKS;
  int n0    = blockrow * BN;
  int mbase = split * MSPL;

  // Gram A-frags: A[m=l16][k=quad*8+j] = vn[h][n0+rt*16+l16][kh*32+quad*8+j]
  short8 aG[2][2];
  #pragma unroll
  for (int rt = 0; rt < 2; rt++)
    #pragma unroll
    for (int kh = 0; kh < 2; kh++) {
      const unsigned short* p =
          vn + ((size_t)h * NN + n0 + rt * 16 + l16) * DH + kh * 32 + quad * 8;
      aG[rt][kh] = *(const short8*)p;
    }

  f32x4 xf[2][4];
  #pragma unroll
  for (int rt = 0; rt < 2; rt++)
    #pragma unroll
    for (int nt = 0; nt < 4; nt++) xf[rt][nt] = (f32x4){0.f, 0.f, 0.f, 0.f};

  float zacc = 0.f, eacc = 0.f;
  int rr    = tid >> 4;           // 0..31: reduction row
  int n_red = n0 + rr;
  int bs_red = (n_red / 10) * 10;
  int nA[2], bsA[2];
  #pragma unroll
  for (int rt = 0; rt < 2; rt++) {
    nA[rt] = n0 + rt * 16 + l16;
    bsA[rt] = (nA[rt] / 10) * 10;
  }

  for (int ch = 0; ch < CHUNKS; ch++) {
    int m0c = mbase + ch * BM;

    // --- Gram: S[r][mm] = vn_row . vn_col --------------------------------
    short8 bG[2][2];
    #pragma unroll
    for (int ct = 0; ct < 2; ct++)
      #pragma unroll
      for (int kh = 0; kh < 2; kh++) {
        const unsigned short* p =
            vn + ((size_t)h * NN + m0c + ct * 16 + l16) * DH + kh * 32 + quad * 8;
        bG[ct][kh] = *(const short8*)p;
      }
    f32x4 s[2][2];
    #pragma unroll
    for (int rt = 0; rt < 2; rt++)
      #pragma unroll
      for (int ct = 0; ct < 2; ct++) {
        f32x4 c = (f32x4){0.f, 0.f, 0.f, 0.f};
        c = __builtin_amdgcn_mfma_f32_16x16x32_bf16(aG[rt][0], bG[ct][0], c, 0, 0, 0);
        c = __builtin_amdgcn_mfma_f32_16x16x32_bf16(aG[rt][1], bG[ct][1], c, 0, 0, 0);
        s[rt][ct] = c;
      }

    __syncthreads();   // previous chunk's Ssc readers done
    #pragma unroll
    for (int rt = 0; rt < 2; rt++)
      #pragma unroll
      for (int ct = 0; ct < 2; ct++)
        #pragma unroll
        for (int g = 0; g < 4; g++)
          Ssc[h][rt * 16 + quad * 4 + g][ct * 16 + l16] = s[rt][ct][g];
    __syncthreads();   // Ssc visible

    // --- head reduction: R, Z, Esel --------------------------------------
    #pragma unroll
    for (int ii = 0; ii < 2; ii++) {
      int mm = l16 * 2 + ii;
      float sum = 0.f;
      #pragma unroll
      for (int hh = 0; hh < HEADS; hh++) sum += Ssc[hh][rr][mm];
      float R = sum * 0.125f;
      int mg = m0c + mm;
      bool zz = (mg >= bs_red) && (mg < bs_red + 9) && (mg != n_red);
      float e = __expf(zz ? 0.f : R);
      zacc += e;
      if (R > 0.75f) eacc += e;
      Rg[(size_t)n_red * NN + mg] = R;
    }

    // --- second GEMM: X += (S*mask) . V ----------------------------------
    short8 aX[2];
    #pragma unroll
    for (int rt = 0; rt < 2; rt++) {
      const float* sp = &Ssc[h][rt * 16 + l16][quad * 8];
      short8 a;
      #pragma unroll
      for (int j = 0; j < 8; j++) {
        int mg = m0c + quad * 8 + j;
        float sv = sp[j];
        bool zz = (mg >= bsA[rt]) && (mg < bsA[rt] + 9) && (mg != nA[rt]);
        a[j] = (short)f2b(zz ? 0.f : sv);
      }
      aX[rt] = a;
    }
    #pragma unroll
    for (int nt = 0; nt < 4; nt++) {
      const unsigned short* p =
          vT + ((size_t)h * DH + nt * 16 + l16) * NN + m0c + quad * 8;
      short8 bX = *(const short8*)p;
      #pragma unroll
      for (int rt = 0; rt < 2; rt++)
        xf[rt][nt] = __builtin_amdgcn_mfma_f32_16x16x32_bf16(aX[rt], bX, xf[rt][nt], 0, 0, 0);
    }
  }

  // --- epilogue ----------------------------------------------------------
  #pragma unroll
  for (int rt = 0; rt < 2; rt++)
    #pragma unroll
    for (int nt = 0; nt < 4; nt++)
      #pragma unroll
      for (int g = 0; g < 4; g++) {
        int row = n0 + rt * 16 + quad * 4 + g;
        int col = h * DH + nt * 16 + l16;
        atomicAdd(&Xacc[(size_t)row * CC + col], xf[rt][nt][g]);
      }
  #pragma unroll
  for (int off = 8; off >= 1; off >>= 1) {
    zacc += __shfl_xor(zacc, off, 16);
    eacc += __shfl_xor(eacc, off, 16);
  }
  if (l16 == 0) {
    atomicAdd(&Zg[n_red], zacc);
    atomicAdd(&Eg[n_red], eacc);
  }
}

// ---------------------------------------------------------------------------
// Kernel 3a: sim_round2[n][m] = (R>0.75) ? exp(mask? 0 : R) / (Esel + EPS*Z) : 0
__global__ void k_soft(const float* __restrict__ Rg, const float* __restrict__ Zg,
                       const float* __restrict__ Eg, float* __restrict__ out2) {
  size_t idx = ((size_t)blockIdx.x * blockDim.x + threadIdx.x) * 4;
  int n  = (int)(idx / NN);
  int m0 = (int)(idx % NN);
  f32x4 R4 = *(const f32x4*)(Rg + idx);
  float rd = 1.0f / (Eg[n] + 1e-8f * Zg[n]);
  int bsn = (n / 10) * 10;
  f32x4 o;
  #pragma unroll
  for (int j = 0; j < 4; j++) {
    int m = m0 + j;
    float r = R4[j];
    bool zz = (m >= bsn) && (m < bsn + 9) && (m != n);
    float e = __expf(zz ? 0.f : r);
    o[j] = (r > 0.75f) ? e * rd : 0.f;
  }
  *(f32x4*)(out2 + idx) = o;
}

// ---------------------------------------------------------------------------
// Kernel 3b: out[n][0..511] = Xacc[n][c]   (output row stride 1024, f32)
__global__ void k_xout(const float* __restrict__ Xacc, float* __restrict__ out) {
  size_t idx = ((size_t)blockIdx.x * blockDim.x + threadIdx.x) * 4;
  int n = (int)(idx >> 9);
  int c = (int)(idx & 511);
  f32x4 x = *(const f32x4*)(Xacc + idx);
  *(f32x4*)(out + (size_t)n * (2 * CC) + c) = x;
}

// ---------------------------------------------------------------------------
extern "C" void kernel_launch(void* const* d_in, const int* in_sizes, int n_in,
                              void* d_out, int out_size, void* d_ws, size_t ws_size,
                              hipStream_t stream) {
  // All fp32 I/O; only v_cls = d_in[1] is live.
  const float* v = (const float*)d_in[1];
  float* out = (float*)d_out;

  // workspace carve (~54.1 MB):
  // [Xacc f32 3200*512][Z f32 3200][E f32 3200][vn bf16 8*3200*64][vT bf16 8*3200*64][R f32 3200*3200]
  float* Xacc = (float*)d_ws;
  float* Zg = Xacc + (size_t)NN * CC;
  float* Eg = Zg + NN;
  unsigned short* vn = (unsigned short*)(Eg + NN);
  unsigned short* vT = vn + (size_t)HEADS * NN * DH;
  float* Rg = (float*)(vT + (size_t)HEADS * NN * DH);

  hipMemsetAsync(d_ws, 0, ((size_t)NN * CC + 2 * NN) * sizeof(float), stream);
  k_norm<<<dim3(NN * HEADS / 4), dim3(256), 0, stream>>>(v, vn, out);
  k_transpose<<<dim3(HEADS * (NN / 64)), dim3(256), 0, stream>>>(v, vT);
  k_main<<<dim3(ROWBLKS * NSPLIT), dim3(512), 0, stream>>>(vn, vT, Rg, Xacc, Zg, Eg);
  k_soft<<<dim3(NN * NN / 1024), dim3(256), 0, stream>>>(Rg, Zg, Eg, out + (size_t)NN * 2 * CC);
  k_xout<<<dim3(NN * CC / 1024), dim3(256), 0, stream>>>(Xacc, out);
}

// Round 3
// 209.800 us; speedup vs baseline: 1.0746x; 1.0746x over previous
//
#include <hip/hip_runtime.h>

// Attention_msa_TwoStream. Only v_cls (d_in[1]) feeds the outputs; the
// qkv-MLP / q / k / softmax(qk) are dead code in the reference.
// N=3200, H=8, d=64, C=512. All I/O fp32. Internals use bf16 MFMA.
// Outputs: x_out (3200x1024 f32) ++ sim_round2 (3200x3200 f32).

#define NN 3200
#define HEADS 8
#define DH 64
#define CC 512          // HEADS*DH
#define BN 32           // rows per block in main kernel
#define BM 64           // m-chunk (64: 32 MFMA per chunk per wave)
#define NSPLIT 5
#define MSPL (NN / NSPLIT)   // 640
#define CHUNKS (MSPL / BM)   // 10
#define ROWBLKS (NN / BN)    // 100
#define SPAD 68              // S row stride (68 = 4 mod 32 -> 2-way banks, free)

typedef __attribute__((ext_vector_type(8))) short short8;   // 8 bf16 (4 VGPRs)
typedef __attribute__((ext_vector_type(4))) float f32x4;

static __device__ __forceinline__ unsigned short f2b(float f) {
  union { float f; unsigned u; } x; x.f = f;
  unsigned u = x.u;
  unsigned r = u + 0x7FFFu + ((u >> 16) & 1u);   // RTN-even
  return (unsigned short)(r >> 16);
}

// ---------------------------------------------------------------------------
// Kernel 1 (fused prep): per-(n,h) L2 norm -> vn[h][n][64] bf16;
// raw V transposed per head -> vT[h][j][n] bf16; x_ori half of out (f32).
// Block = (head h, 64-row tile). 256 thr = 4 waves x 16 rows each.
__global__ __launch_bounds__(256) void k_prep(const float* __restrict__ v,
                                              unsigned short* __restrict__ vn,
                                              unsigned short* __restrict__ vT,
                                              float* __restrict__ out) {
  __shared__ unsigned short tile[DH][66];
  int h  = blockIdx.x & 7;
  int n0 = (int)(blockIdx.x >> 3) * 64;
  int j  = threadIdx.x & 63;       // dim within head
  int r0 = threadIdx.x >> 6;       // wave id = row group
  float val[16];
  #pragma unroll
  for (int i = 0; i < 16; i++) {
    int n = n0 + r0 * 16 + i;
    val[i] = v[(size_t)n * CC + h * DH + j];
    tile[j][r0 * 16 + i] = f2b(val[i]);                    // raw V for vT
    out[(size_t)n * (2 * CC) + CC + h * DH + j] = val[i];  // x_ori
  }
  #pragma unroll
  for (int i = 0; i < 16; i++) {
    float ss = val[i] * val[i];
    #pragma unroll
    for (int off = 32; off >= 1; off >>= 1) ss += __shfl_xor(ss, off, 64);
    float inv = 1.0f / (sqrtf(ss) + 1e-8f);
    int n = n0 + r0 * 16 + i;
    vn[((size_t)h * NN + n) * DH + j] = f2b(val[i] * inv);
  }
  __syncthreads();
  int r = threadIdx.x & 63, jb = (threadIdx.x >> 6) * 16;
  #pragma unroll
  for (int i = 0; i < 16; i++) {
    int jj = jb + i;
    vT[((size_t)h * DH + jj) * NN + n0 + r] = tile[jj][r];
  }
}

// ---------------------------------------------------------------------------
// Kernel 2: fused main. 512 thr = 8 waves = 8 heads; BN=32 rows, one of
// NSPLIT m-ranges in BM=64 chunks.
//  per chunk: Gram MFMA (S_h) -> LDS -> head reduction (R -> signed-e store,
//  Z/Esel accum) -> masked S' as bf16 A-frags -> MFMA X += S' * V.
__global__ __launch_bounds__(512, 4) void k_main(const unsigned short* __restrict__ vn,
                                                 const unsigned short* __restrict__ vT,
                                                 float* __restrict__ Rg,
                                                 float* __restrict__ Xacc,
                                                 float* __restrict__ Zg,
                                                 float* __restrict__ Eg) {
  __shared__ __align__(16) float Ssc[HEADS][BN][SPAD];   // 69632 B -> 2 blk/CU
  int tid  = threadIdx.x;
  int h    = tid >> 6;
  int lane = tid & 63;
  int quad = lane >> 4, l16 = lane & 15;
  int blockrow = (int)blockIdx.x % ROWBLKS;
  int split    = (int)blockIdx.x / ROWBLKS;
  int n0    = blockrow * BN;
  int mbase = split * MSPL;

  // Gram A-frags (persistent): A[m=l16][k=quad*8+j]
  short8 aG[2][2];
  #pragma unroll
  for (int rt = 0; rt < 2; rt++)
    #pragma unroll
    for (int kh = 0; kh < 2; kh++)
      aG[rt][kh] = *(const short8*)(vn + ((size_t)h * NN + n0 + rt * 16 + l16) * DH +
                                    kh * 32 + quad * 8);

  f32x4 xf[2][4];
  #pragma unroll
  for (int rt = 0; rt < 2; rt++)
    #pragma unroll
    for (int nt = 0; nt < 4; nt++) xf[rt][nt] = (f32x4){0.f, 0.f, 0.f, 0.f};

  float zacc = 0.f, eacc = 0.f;
  int rr    = tid >> 4;            // 0..31: reduction row
  int n_red = n0 + rr;
  int bs_red = (n_red / 10) * 10;
  int nA[2], bsA[2];
  #pragma unroll
  for (int rt = 0; rt < 2; rt++) {
    nA[rt] = n0 + rt * 16 + l16;
    bsA[rt] = (nA[rt] / 10) * 10;
  }

  for (int ch = 0; ch < CHUNKS; ch++) {
    int m0c = mbase + ch * BM;

    // --- Gram: S[r][m] = vn_row . vn_col (2x4 tiles of 16x16, K=64) ------
    f32x4 s[2][4];
    #pragma unroll
    for (int ct = 0; ct < 4; ct++) {
      const unsigned short* p =
          vn + ((size_t)h * NN + m0c + ct * 16 + l16) * DH + quad * 8;
      short8 b0 = *(const short8*)p;
      short8 b1 = *(const short8*)(p + 32);
      #pragma unroll
      for (int rt = 0; rt < 2; rt++) {
        f32x4 c = (f32x4){0.f, 0.f, 0.f, 0.f};
        c = __builtin_amdgcn_mfma_f32_16x16x32_bf16(aG[rt][0], b0, c, 0, 0, 0);
        c = __builtin_amdgcn_mfma_f32_16x16x32_bf16(aG[rt][1], b1, c, 0, 0, 0);
        s[rt][ct] = c;
      }
    }

    __syncthreads();   // previous chunk's Ssc readers done
    #pragma unroll
    for (int rt = 0; rt < 2; rt++)
      #pragma unroll
      for (int ct = 0; ct < 4; ct++)
        #pragma unroll
        for (int g = 0; g < 4; g++)
          Ssc[h][rt * 16 + quad * 4 + g][ct * 16 + l16] = s[rt][ct][g];
    __syncthreads();   // Ssc visible

    // --- head reduction: R -> signed-e store, Z / Esel -------------------
    {
      f32x4 sum = (f32x4){0.f, 0.f, 0.f, 0.f};
      #pragma unroll
      for (int hh = 0; hh < HEADS; hh++) {
        f32x4 t = *(const f32x4*)&Ssc[hh][rr][l16 * 4];
        sum += t;
      }
      f32x4 o;
      #pragma unroll
      for (int jj = 0; jj < 4; jj++) {
        float R = sum[jj] * 0.125f;
        int mg = m0c + l16 * 4 + jj;
        bool zz = (mg >= bs_red) && (mg < bs_red + 9) && (mg != n_red);
        float e = __expf(zz ? 0.f : R);
        zacc += e;
        bool sel = (R > 0.75f);
        if (sel) eacc += e;
        o[jj] = sel ? e : -e;      // sign encodes sim_mask
      }
      *(f32x4*)(Rg + (size_t)n_red * NN + m0c + l16 * 4) = o;
    }

    // --- second GEMM: X += (S*mask) . V ----------------------------------
    short8 aX[2][2];
    #pragma unroll
    for (int rt = 0; rt < 2; rt++)
      #pragma unroll
      for (int kh = 0; kh < 2; kh++) {
        const float* sp = &Ssc[h][rt * 16 + l16][kh * 32 + quad * 8];
        f32x4 v0 = *(const f32x4*)sp;
        f32x4 v1 = *(const f32x4*)(sp + 4);
        short8 a;
        #pragma unroll
        for (int j = 0; j < 8; j++) {
          int mg = m0c + kh * 32 + quad * 8 + j;
          float sv = (j < 4) ? v0[j] : v1[j - 4];
          bool zz = (mg >= bsA[rt]) && (mg < bsA[rt] + 9) && (mg != nA[rt]);
          a[j] = (short)f2b(zz ? 0.f : sv);
        }
        aX[rt][kh] = a;
      }
    #pragma unroll
    for (int nt = 0; nt < 4; nt++) {
      const unsigned short* p =
          vT + ((size_t)h * DH + nt * 16 + l16) * NN + m0c + quad * 8;
      short8 b0 = *(const short8*)p;
      short8 b1 = *(const short8*)(p + 32);
      #pragma unroll
      for (int rt = 0; rt < 2; rt++) {
        xf[rt][nt] = __builtin_amdgcn_mfma_f32_16x16x32_bf16(aX[rt][0], b0, xf[rt][nt], 0, 0, 0);
        xf[rt][nt] = __builtin_amdgcn_mfma_f32_16x16x32_bf16(aX[rt][1], b1, xf[rt][nt], 0, 0, 0);
      }
    }
  }

  // --- epilogue ----------------------------------------------------------
  #pragma unroll
  for (int rt = 0; rt < 2; rt++)
    #pragma unroll
    for (int nt = 0; nt < 4; nt++)
      #pragma unroll
      for (int g = 0; g < 4; g++) {
        int row = n0 + rt * 16 + quad * 4 + g;
        int col = h * DH + nt * 16 + l16;
        atomicAdd(&Xacc[(size_t)row * CC + col], xf[rt][nt][g]);
      }
  #pragma unroll
  for (int off = 8; off >= 1; off >>= 1) {
    zacc += __shfl_xor(zacc, off, 16);
    eacc += __shfl_xor(eacc, off, 16);
  }
  if (l16 == 0) {
    atomicAdd(&Zg[n_red], zacc);
    atomicAdd(&Eg[n_red], eacc);
  }
}

// ---------------------------------------------------------------------------
// Kernel 3a: out2[n][m] = s>0 ? s / (Esel + EPS*Z) : 0   (s = signed-e)
__global__ void k_soft(const float* __restrict__ Rg, const float* __restrict__ Zg,
                       const float* __restrict__ Eg, float* __restrict__ out2) {
  unsigned int ui = (blockIdx.x * blockDim.x + threadIdx.x) * 4u;
  unsigned int n  = ui / NN;
  size_t idx = (size_t)ui;
  f32x4 s4 = *(const f32x4*)(Rg + idx);
  float rd = 1.0f / (Eg[n] + 1e-8f * Zg[n]);
  f32x4 o;
  #pragma unroll
  for (int j = 0; j < 4; j++) o[j] = (s4[j] > 0.f) ? s4[j] * rd : 0.f;
  *(f32x4*)(out2 + idx) = o;
}

// ---------------------------------------------------------------------------
// Kernel 3b: out[n][0..511] = Xacc[n][c]   (output row stride 1024, f32)
__global__ void k_xout(const float* __restrict__ Xacc, float* __restrict__ out) {
  unsigned int ui = (blockIdx.x * blockDim.x + threadIdx.x) * 4u;
  int n = (int)(ui >> 9);
  int c = (int)(ui & 511);
  f32x4 x = *(const f32x4*)(Xacc + ui);
  *(f32x4*)(out + (size_t)n * (2 * CC) + c) = x;
}

// ---------------------------------------------------------------------------
extern "C" void kernel_launch(void* const* d_in, const int* in_sizes, int n_in,
                              void* d_out, int out_size, void* d_ws, size_t ws_size,
                              hipStream_t stream) {
  const float* v = (const float*)d_in[1];   // only live input
  float* out = (float*)d_out;

  // workspace carve (~54.1 MB):
  // [Xacc f32 3200*512][Z f32 3200][E f32 3200][vn bf16 8*3200*64][vT bf16 8*3200*64][R f32 3200*3200]
  float* Xacc = (float*)d_ws;
  float* Zg = Xacc + (size_t)NN * CC;
  float* Eg = Zg + NN;
  unsigned short* vn = (unsigned short*)(Eg + NN);
  unsigned short* vT = vn + (size_t)HEADS * NN * DH;
  float* Rg = (float*)(vT + (size_t)HEADS * NN * DH);

  hipMemsetAsync(d_ws, 0, ((size_t)NN * CC + 2 * NN) * sizeof(float), stream);
  k_prep<<<dim3(HEADS * (NN / 64)), dim3(256), 0, stream>>>(v, vn, vT, out);
  k_main<<<dim3(ROWBLKS * NSPLIT), dim3(512), 0, stream>>>(vn, vT, Rg, Xacc, Zg, Eg);
  k_soft<<<dim3(NN * NN / 1024), dim3(256), 0, stream>>>(Rg, Zg, Eg, out + (size_t)NN * 2 * CC);
  k_xout<<<dim3(NN * CC / 1024), dim3(256), 0, stream>>>(Xacc, out);
}

// Round 4
// 198.677 us; speedup vs baseline: 1.1348x; 1.0560x over previous
//
#include <hip/hip_runtime.h>

// Attention_msa_TwoStream. Only v_cls (d_in[1]) feeds outputs (MLP/q/k dead).
// N=3200, H=8, d=64, C=512; fp32 I/O; bf16 MFMA internals.
// Key algebra: R = (1/8) vnfull.vnfull^T (K=512 Gram, drives sim_round2);
// X_h = (S_h*mask).V_h = vn_h.(vn_h^T V_h) - block-zone correction (G_h is 64x64).

#define NN 3200
#define HEADS 8
#define DH 64
#define CC 512

typedef __attribute__((ext_vector_type(8))) short short8;   // 8 bf16
typedef __attribute__((ext_vector_type(4))) float f32x4;

static __device__ __forceinline__ unsigned short f2b(float f) {
  union { float f; unsigned u; } x; x.f = f;
  unsigned r = x.u + 0x7FFFu + ((x.u >> 16) & 1u);
  return (unsigned short)(r >> 16);
}
static __device__ __forceinline__ float b2f(unsigned short s) {
  union { unsigned u; float f; } x; x.u = ((unsigned)s) << 16; return x.f;
}

// ---------------------------------------------------------------------------
// k_prep: per-(n,h) L2 norm. Writes vnfull[n][512] bf16, vnT[h][k][n] bf16,
// vT[h][d][n] bf16 (raw V transposed), x_ori half of out (f32).
// Block = (head h, 64-row tile); 256 thr.
__global__ __launch_bounds__(256) void k_prep(const float* __restrict__ v,
                                              unsigned short* __restrict__ vnfull,
                                              unsigned short* __restrict__ vnT,
                                              unsigned short* __restrict__ vT,
                                              float* __restrict__ out) {
  __shared__ unsigned short tileV[DH][66];
  __shared__ unsigned short tileN[DH][66];
  int h  = blockIdx.x & 7;
  int n0 = (int)(blockIdx.x >> 3) * 64;
  int j  = threadIdx.x & 63;
  int r0 = threadIdx.x >> 6;       // 0..3
  #pragma unroll
  for (int i = 0; i < 16; i++) {
    int n = n0 + r0 * 16 + i;
    float val = v[(size_t)n * CC + h * DH + j];
    float ss = val * val;
    #pragma unroll
    for (int off = 32; off >= 1; off >>= 1) ss += __shfl_xor(ss, off, 64);
    float inv = 1.0f / (sqrtf(ss) + 1e-8f);
    unsigned short un = f2b(val * inv);
    tileV[j][r0 * 16 + i] = f2b(val);
    tileN[j][r0 * 16 + i] = un;
    vnfull[(size_t)n * CC + h * DH + j] = un;
    out[(size_t)n * (2 * CC) + CC + h * DH + j] = val;   // x_ori
  }
  __syncthreads();
  int r = threadIdx.x & 63;
  #pragma unroll
  for (int i = 0; i < 16; i++) {
    int jj = r0 * 16 + i;
    vT[((size_t)h * DH + jj) * NN + n0 + r]  = tileV[jj][r];
    vnT[((size_t)h * DH + jj) * NN + n0 + r] = tileN[jj][r];
  }
}

// ---------------------------------------------------------------------------
// k_gacc: Gt_f32[h][d][k] += sum_m V[m][d] * vn[m][k]   (A=vT rows, B=vnT rows)
// grid = 8 heads x 10 chunks (320 rows); 256 thr = 4 waves (16 d-rows each).
__global__ __launch_bounds__(256) void k_gacc(const unsigned short* __restrict__ vT,
                                              const unsigned short* __restrict__ vnT,
                                              float* __restrict__ Gf) {
  int h  = (int)blockIdx.x & 7;
  int ch = (int)blockIdx.x >> 3;
  int m0 = ch * 320;
  int w = threadIdx.x >> 6;
  int lane = threadIdx.x & 63;
  int quad = lane >> 4, l16 = lane & 15;
  f32x4 acc[4];
  #pragma unroll
  for (int ct = 0; ct < 4; ct++) acc[ct] = (f32x4){0.f, 0.f, 0.f, 0.f};
  const unsigned short* ap = vT  + ((size_t)h * DH + w * 16 + l16) * NN + quad * 8;
  for (int t = 0; t < 10; t++) {
    int mm = m0 + t * 32;
    short8 a = *(const short8*)(ap + mm);
    #pragma unroll
    for (int ct = 0; ct < 4; ct++) {
      short8 b = *(const short8*)(vnT + ((size_t)h * DH + ct * 16 + l16) * NN + mm + quad * 8);
      acc[ct] = __builtin_amdgcn_mfma_f32_16x16x32_bf16(a, b, acc[ct], 0, 0, 0);
    }
  }
  // C-layout: row d = w*16+quad*4+g, col k = ct*16+l16
  #pragma unroll
  for (int ct = 0; ct < 4; ct++)
    #pragma unroll
    for (int g = 0; g < 4; g++)
      atomicAdd(&Gf[(size_t)h * 4096 + (w * 16 + quad * 4 + g) * 64 + ct * 16 + l16],
                acc[ct][g]);
}

// k_gcvt: Gt bf16 <- Gf f32 (flat 32768)
__global__ void k_gcvt(const float* __restrict__ Gf, unsigned short* __restrict__ Gt) {
  int i = (blockIdx.x * 256 + threadIdx.x) * 4;
  f32x4 x = *(const f32x4*)(Gf + i);
  unsigned short o0 = f2b(x[0]), o1 = f2b(x[1]), o2 = f2b(x[2]), o3 = f2b(x[3]);
  unsigned long long wv = (unsigned long long)o0 | ((unsigned long long)o1 << 16) |
                          ((unsigned long long)o2 << 32) | ((unsigned long long)o3 << 48);
  *(unsigned long long*)(Gt + i) = wv;
}

// ---------------------------------------------------------------------------
// k_rgemm: R = (1/8) vnfull . vnfull^T, K=512 bf16 MFMA, direct-global loads.
// Epilogue: e = exp(blockmask? 0 : R); Rg = (R>0.75)? e : -e; Z/E row atomics.
// Block 256 thr = 4 waves (2x2); block tile 64 rows x 128 cols; grid 50x25.
__global__ __launch_bounds__(256) void k_rgemm(const unsigned short* __restrict__ vnfull,
                                               float* __restrict__ Rg,
                                               float* __restrict__ Zg,
                                               float* __restrict__ Eg) {
  int b = (int)blockIdx.x;
  int n0 = (b % 50) * 64;
  int m0 = (b / 50) * 128;
  int wv = threadIdx.x >> 6;
  int wr = wv >> 1, wc = wv & 1;
  int lane = threadIdx.x & 63;
  int quad = lane >> 4, l16 = lane & 15;

  f32x4 acc[2][4];
  #pragma unroll
  for (int rt = 0; rt < 2; rt++)
    #pragma unroll
    for (int ct = 0; ct < 4; ct++) acc[rt][ct] = (f32x4){0.f, 0.f, 0.f, 0.f};

  const unsigned short* aB = vnfull + (size_t)(n0 + wr * 32 + l16) * CC + quad * 8;
  const unsigned short* bB = vnfull + (size_t)(m0 + wc * 64 + l16) * CC + quad * 8;
  for (int kk = 0; kk < 16; kk++) {
    int k0 = kk * 32;
    short8 a0 = *(const short8*)(aB + k0);
    short8 a1 = *(const short8*)(aB + 16 * CC + k0);
    #pragma unroll
    for (int ct = 0; ct < 4; ct++) {
      short8 bb = *(const short8*)(bB + (size_t)ct * 16 * CC + k0);
      acc[0][ct] = __builtin_amdgcn_mfma_f32_16x16x32_bf16(a0, bb, acc[0][ct], 0, 0, 0);
      acc[1][ct] = __builtin_amdgcn_mfma_f32_16x16x32_bf16(a1, bb, acc[1][ct], 0, 0, 0);
    }
  }

  // epilogue: rows n = n0+wr*32+rt*16+quad*4+g, cols m = m0+wc*64+ct*16+l16
  float zs[2][4], es[2][4];
  int nrow[2][4], bsr[2][4];
  #pragma unroll
  for (int rt = 0; rt < 2; rt++)
    #pragma unroll
    for (int g = 0; g < 4; g++) {
      zs[rt][g] = 0.f; es[rt][g] = 0.f;
      int n = n0 + wr * 32 + rt * 16 + quad * 4 + g;
      nrow[rt][g] = n;
      bsr[rt][g] = (n / 10) * 10;
    }
  #pragma unroll
  for (int rt = 0; rt < 2; rt++)
    #pragma unroll
    for (int ct = 0; ct < 4; ct++) {
      int m = m0 + wc * 64 + ct * 16 + l16;
      #pragma unroll
      for (int g = 0; g < 4; g++) {
        float R = acc[rt][ct][g] * 0.125f;
        int n = nrow[rt][g], bs = bsr[rt][g];
        bool zz = (m >= bs) && (m < bs + 9) && (m != n);
        float e = __expf(zz ? 0.f : R);
        bool sel = (R > 0.75f);
        zs[rt][g] += e;
        if (sel) es[rt][g] += e;
        Rg[(size_t)n * NN + m] = sel ? e : -e;
      }
    }
  #pragma unroll
  for (int rt = 0; rt < 2; rt++)
    #pragma unroll
    for (int g = 0; g < 4; g++) {
      float z = zs[rt][g], e = es[rt][g];
      #pragma unroll
      for (int off = 8; off >= 1; off >>= 1) {
        z += __shfl_xor(z, off, 64);
        e += __shfl_xor(e, off, 64);
      }
      if (l16 == 0) {
        atomicAdd(&Zg[nrow[rt][g]], z);
        atomicAdd(&Eg[nrow[rt][g]], e);
      }
    }
}

// ---------------------------------------------------------------------------
// k_x: X_h[n][d] = sum_k vn[n][h*64+k] * G[h][k][d]  -  zone correction.
// Block 512 thr = 8 waves = 8 heads; 16 rows per block; barrier-free.
__global__ __launch_bounds__(512) void k_x(const unsigned short* __restrict__ vnfull,
                                           const unsigned short* __restrict__ Gt,
                                           const float* __restrict__ v,
                                           float* __restrict__ out) {
  __shared__ float Szone[16][HEADS][12];
  int h    = threadIdx.x >> 6;
  int lane = threadIdx.x & 63;
  int quad = lane >> 4, l16 = lane & 15;
  int n0 = (int)blockIdx.x * 16;
  int lo = (n0 / 10) * 10;
  int hi = ((n0 + 15) / 10) * 10 + 10;          // <= 3200, width <= 30

  // A-frags: rows n0..n0+15, dims h*64..h*64+63
  short8 aZ[2];
  #pragma unroll
  for (int kh = 0; kh < 2; kh++)
    aZ[kh] = *(const short8*)(vnfull + (size_t)(n0 + l16) * CC + h * DH + kh * 32 + quad * 8);

  // --- phase B: zone Gram S[n][m] for m in [lo, lo+32) ---------------------
  #pragma unroll
  for (int ct = 0; ct < 2; ct++) {
    int rB = lo + ct * 16 + l16;
    int rC = rB < NN ? rB : NN - 1;              // clamp OOB (values unused)
    short8 b0 = *(const short8*)(vnfull + (size_t)rC * CC + h * DH + quad * 8);
    short8 b1 = *(const short8*)(vnfull + (size_t)rC * CC + h * DH + 32 + quad * 8);
    f32x4 c = (f32x4){0.f, 0.f, 0.f, 0.f};
    c = __builtin_amdgcn_mfma_f32_16x16x32_bf16(aZ[0], b0, c, 0, 0, 0);
    c = __builtin_amdgcn_mfma_f32_16x16x32_bf16(aZ[1], b1, c, 0, 0, 0);
    // lane holds rows n_i=quad*4+g, col m = lo+ct*16+l16
    int m = lo + ct * 16 + l16;
    #pragma unroll
    for (int g = 0; g < 4; g++) {
      int n = n0 + quad * 4 + g;
      int bs = (n / 10) * 10;
      if (m >= bs && m < bs + 9 && m != n)
        Szone[quad * 4 + g][h][m - bs] = c[g];
    }
  }

  // --- phase C: main term via G ------------------------------------------
  f32x4 xr[4];
  #pragma unroll
  for (int nt = 0; nt < 4; nt++) {
    short8 g0 = *(const short8*)(Gt + (size_t)h * 4096 + (nt * 16 + l16) * 64 + quad * 8);
    short8 g1 = *(const short8*)(Gt + (size_t)h * 4096 + (nt * 16 + l16) * 64 + 32 + quad * 8);
    f32x4 c = (f32x4){0.f, 0.f, 0.f, 0.f};
    c = __builtin_amdgcn_mfma_f32_16x16x32_bf16(aZ[0], g0, c, 0, 0, 0);
    c = __builtin_amdgcn_mfma_f32_16x16x32_bf16(aZ[1], g1, c, 0, 0, 0);
    xr[nt] = c;
  }

  // --- correction: subtract zone contributions ---------------------------
  int bs_m = lo, moff = 0;
  for (int m = lo; m < hi; ++m, ++moff) {
    if (moff == 10) { moff = 0; bs_m += 10; }
    float vload[4];
    #pragma unroll
    for (int nt = 0; nt < 4; nt++)
      vload[nt] = v[(size_t)m * CC + h * DH + nt * 16 + l16];
    #pragma unroll
    for (int g = 0; g < 4; g++) {
      int n = n0 + quad * 4 + g;
      float s = 0.f;
      if (moff < 9 && n >= bs_m && n < bs_m + 10 && n != m)
        s = Szone[quad * 4 + g][h][moff];
      #pragma unroll
      for (int nt = 0; nt < 4; nt++) xr[nt][g] -= s * vload[nt];
    }
  }

  // --- store: out[n][h*64 + nt*16 + l16], rows n = n0+quad*4+g ------------
  #pragma unroll
  for (int nt = 0; nt < 4; nt++)
    #pragma unroll
    for (int g = 0; g < 4; g++)
      out[(size_t)(n0 + quad * 4 + g) * (2 * CC) + h * DH + nt * 16 + l16] = xr[nt][g];
}

// ---------------------------------------------------------------------------
// k_soft: out2[n][m] = s>0 ? s / (Esel + EPS*Z) : 0   (s = signed-e)
__global__ void k_soft(const float* __restrict__ Rg, const float* __restrict__ Zg,
                       const float* __restrict__ Eg, float* __restrict__ out2) {
  unsigned int ui = (blockIdx.x * blockDim.x + threadIdx.x) * 4u;
  unsigned int n = ui / NN;
  f32x4 s4 = *(const f32x4*)(Rg + (size_t)ui);
  float rd = 1.0f / (Eg[n] + 1e-8f * Zg[n]);
  f32x4 o;
  #pragma unroll
  for (int j = 0; j < 4; j++) o[j] = (s4[j] > 0.f) ? s4[j] * rd : 0.f;
  *(f32x4*)(out2 + (size_t)ui) = o;
}

// ---------------------------------------------------------------------------
extern "C" void kernel_launch(void* const* d_in, const int* in_sizes, int n_in,
                              void* d_out, int out_size, void* d_ws, size_t ws_size,
                              hipStream_t stream) {
  const float* v = (const float*)d_in[1];   // only live input
  float* out = (float*)d_out;

  // ws carve (~51 MB): [Zg 3200][Eg 3200][Gf 32768]f32 [Gt 32768]bf16
  //                    [vnfull][vnT][vT] 3x 1638400 bf16  [Rg 3200*3200]f32
  float* Zg = (float*)d_ws;
  float* Eg = Zg + NN;
  float* Gf = Eg + NN;
  unsigned short* Gt = (unsigned short*)(Gf + HEADS * DH * DH);
  unsigned short* vnfull = Gt + HEADS * DH * DH;
  unsigned short* vnT = vnfull + (size_t)NN * CC;
  unsigned short* vT  = vnT + (size_t)NN * CC;
  float* Rg = (float*)(vT + (size_t)NN * CC);

  hipMemsetAsync(d_ws, 0, (2 * NN + HEADS * DH * DH) * sizeof(float), stream);
  k_prep<<<dim3(HEADS * (NN / 64)), dim3(256), 0, stream>>>(v, vnfull, vnT, vT, out);
  k_gacc<<<dim3(HEADS * 10), dim3(256), 0, stream>>>(vT, vnT, Gf);
  k_gcvt<<<dim3(HEADS * DH * DH / 1024), dim3(256), 0, stream>>>(Gf, Gt);
  k_rgemm<<<dim3(50 * 25), dim3(256), 0, stream>>>(vnfull, Rg, Zg, Eg);
  k_x<<<dim3(NN / 16), dim3(512), 0, stream>>>(vnfull, Gt, v, out);
  k_soft<<<dim3(NN * NN / 1024), dim3(256), 0, stream>>>(Rg, Zg, Eg, out + (size_t)NN * 2 * CC);
}

// Round 5
// 190.276 us; speedup vs baseline: 1.1849x; 1.0442x over previous
//
#include <hip/hip_runtime.h>

// Attention_msa_TwoStream. Only v_cls (d_in[1]) feeds outputs (MLP/q/k dead).
// N=3200, H=8, d=64, C=512; fp32 I/O; bf16 MFMA internals.
// Algebra: R = (1/8) vnfull.vnfull^T (K=512 Gram -> sim_round2);
// X_h = vn_h.(vn_h^T V_h) - block-zone correction (G_h is 64x64).

#define NN 3200
#define HEADS 8
#define DH 64
#define CC 512

typedef __attribute__((ext_vector_type(8))) short short8;   // 8 bf16
typedef __attribute__((ext_vector_type(4))) float f32x4;

static __device__ __forceinline__ unsigned short f2b(float f) {
  union { float f; unsigned u; } x; x.f = f;
  unsigned r = x.u + 0x7FFFu + ((x.u >> 16) & 1u);
  return (unsigned short)(r >> 16);
}
static __device__ __forceinline__ short8 pack8(f32x4 lo, f32x4 hi) {
  short8 r;
  r[0] = (short)f2b(lo[0]); r[1] = (short)f2b(lo[1]);
  r[2] = (short)f2b(lo[2]); r[3] = (short)f2b(lo[3]);
  r[4] = (short)f2b(hi[0]); r[5] = (short)f2b(hi[1]);
  r[6] = (short)f2b(hi[2]); r[7] = (short)f2b(hi[3]);
  return r;
}

// ---------------------------------------------------------------------------
// k_prep: per-(n,h) L2 norm. Writes vnfull[n][512] bf16, vnT[h][k][n] bf16,
// vT[h][d][n] bf16 (raw V transposed), x_ori half of out (f32).
__global__ __launch_bounds__(256) void k_prep(const float* __restrict__ v,
                                              unsigned short* __restrict__ vnfull,
                                              unsigned short* __restrict__ vnT,
                                              unsigned short* __restrict__ vT,
                                              float* __restrict__ out) {
  __shared__ unsigned short tileV[DH][66];
  __shared__ unsigned short tileN[DH][66];
  int h  = blockIdx.x & 7;
  int n0 = (int)(blockIdx.x >> 3) * 64;
  int j  = threadIdx.x & 63;
  int r0 = threadIdx.x >> 6;       // 0..3
  #pragma unroll
  for (int i = 0; i < 16; i++) {
    int n = n0 + r0 * 16 + i;
    float val = v[(size_t)n * CC + h * DH + j];
    float ss = val * val;
    #pragma unroll
    for (int off = 32; off >= 1; off >>= 1) ss += __shfl_xor(ss, off, 64);
    float inv = 1.0f / (sqrtf(ss) + 1e-8f);
    unsigned short un = f2b(val * inv);
    tileV[j][r0 * 16 + i] = f2b(val);
    tileN[j][r0 * 16 + i] = un;
    vnfull[(size_t)n * CC + h * DH + j] = un;
    out[(size_t)n * (2 * CC) + CC + h * DH + j] = val;   // x_ori
  }
  __syncthreads();
  int r = threadIdx.x & 63;
  #pragma unroll
  for (int i = 0; i < 16; i++) {
    int jj = r0 * 16 + i;
    vT[((size_t)h * DH + jj) * NN + n0 + r]  = tileV[jj][r];
    vnT[((size_t)h * DH + jj) * NN + n0 + r] = tileN[jj][r];
  }
}

// ---------------------------------------------------------------------------
// k_gacc: Gf[h][d][k] += sum_m V[m][d]*vn[m][k]  (A=vT rows, B=vnT rows)
__global__ __launch_bounds__(256) void k_gacc(const unsigned short* __restrict__ vT,
                                              const unsigned short* __restrict__ vnT,
                                              float* __restrict__ Gf) {
  int h  = (int)blockIdx.x & 7;
  int ch = (int)blockIdx.x >> 3;
  int m0 = ch * 320;
  int w = threadIdx.x >> 6;
  int lane = threadIdx.x & 63;
  int quad = lane >> 4, l16 = lane & 15;
  f32x4 acc[4];
  #pragma unroll
  for (int ct = 0; ct < 4; ct++) acc[ct] = (f32x4){0.f, 0.f, 0.f, 0.f};
  const unsigned short* ap = vT + ((size_t)h * DH + w * 16 + l16) * NN + quad * 8;
  for (int t = 0; t < 10; t++) {
    int mm = m0 + t * 32;
    short8 a = *(const short8*)(ap + mm);
    #pragma unroll
    for (int ct = 0; ct < 4; ct++) {
      short8 b = *(const short8*)(vnT + ((size_t)h * DH + ct * 16 + l16) * NN + mm + quad * 8);
      acc[ct] = __builtin_amdgcn_mfma_f32_16x16x32_bf16(a, b, acc[ct], 0, 0, 0);
    }
  }
  #pragma unroll
  for (int ct = 0; ct < 4; ct++)
    #pragma unroll
    for (int g = 0; g < 4; g++)
      atomicAdd(&Gf[(size_t)h * 4096 + (w * 16 + quad * 4 + g) * 64 + ct * 16 + l16],
                acc[ct][g]);
}

// ---------------------------------------------------------------------------
// k_rgemm: R = (1/8) vnfull.vnfull^T, K=512. 256 thr = 4 waves (2x2), each
// wave 64x64 -> block tile 128x128; register double-buffered K-loop (BK=32).
// Epilogue: e=exp(mask?0:R); Rg = (R>0.75)? e : -e; Z/E row atomics.
__global__ __launch_bounds__(256) void k_rgemm(const unsigned short* __restrict__ vnfull,
                                               float* __restrict__ Rg,
                                               float* __restrict__ Zg,
                                               float* __restrict__ Eg) {
  int b = (int)blockIdx.x;
  int n0 = (b % 25) * 128;
  int m0 = (b / 25) * 128;
  int wv = threadIdx.x >> 6;
  int wr = wv >> 1, wc = wv & 1;
  int lane = threadIdx.x & 63;
  int quad = lane >> 4, l16 = lane & 15;

  const unsigned short* aB = vnfull + (size_t)(n0 + wr * 64 + l16) * CC + quad * 8;
  const unsigned short* bB = vnfull + (size_t)(m0 + wc * 64 + l16) * CC + quad * 8;

  f32x4 acc[4][4];
  #pragma unroll
  for (int rt = 0; rt < 4; rt++)
    #pragma unroll
    for (int ct = 0; ct < 4; ct++) acc[rt][ct] = (f32x4){0.f, 0.f, 0.f, 0.f};

  short8 aP[4], bP[4], aQ[4], bQ[4];
  #pragma unroll
  for (int rt = 0; rt < 4; rt++) aP[rt] = *(const short8*)(aB + (size_t)rt * 16 * CC);
  #pragma unroll
  for (int ct = 0; ct < 4; ct++) bP[ct] = *(const short8*)(bB + (size_t)ct * 16 * CC);

  #pragma unroll 1
  for (int kk = 0; kk < 16; kk += 2) {
    int k1 = (kk + 1) * 32;
    #pragma unroll
    for (int rt = 0; rt < 4; rt++) aQ[rt] = *(const short8*)(aB + (size_t)rt * 16 * CC + k1);
    #pragma unroll
    for (int ct = 0; ct < 4; ct++) bQ[ct] = *(const short8*)(bB + (size_t)ct * 16 * CC + k1);
    #pragma unroll
    for (int rt = 0; rt < 4; rt++)
      #pragma unroll
      for (int ct = 0; ct < 4; ct++)
        acc[rt][ct] = __builtin_amdgcn_mfma_f32_16x16x32_bf16(aP[rt], bP[ct], acc[rt][ct], 0, 0, 0);
    if (kk + 2 < 16) {
      int k2 = (kk + 2) * 32;
      #pragma unroll
      for (int rt = 0; rt < 4; rt++) aP[rt] = *(const short8*)(aB + (size_t)rt * 16 * CC + k2);
      #pragma unroll
      for (int ct = 0; ct < 4; ct++) bP[ct] = *(const short8*)(bB + (size_t)ct * 16 * CC + k2);
    }
    #pragma unroll
    for (int rt = 0; rt < 4; rt++)
      #pragma unroll
      for (int ct = 0; ct < 4; ct++)
        acc[rt][ct] = __builtin_amdgcn_mfma_f32_16x16x32_bf16(aQ[rt], bQ[ct], acc[rt][ct], 0, 0, 0);
  }

  // epilogue: rows n = n0+wr*64+rt*16+quad*4+g, cols m = m0+wc*64+ct*16+l16
  #pragma unroll
  for (int rt = 0; rt < 4; rt++) {
    #pragma unroll
    for (int g = 0; g < 4; g++) {
      int n = n0 + wr * 64 + rt * 16 + quad * 4 + g;
      int bs = (n / 10) * 10;
      float z = 0.f, e = 0.f;
      #pragma unroll
      for (int ct = 0; ct < 4; ct++) {
        int m = m0 + wc * 64 + ct * 16 + l16;
        float R = acc[rt][ct][g] * 0.125f;
        bool zz = (m >= bs) && (m < bs + 9) && (m != n);
        float ev = __expf(zz ? 0.f : R);
        bool sel = (R > 0.75f);
        z += ev;
        if (sel) e += ev;
        Rg[(size_t)n * NN + m] = sel ? ev : -ev;
      }
      #pragma unroll
      for (int off = 8; off >= 1; off >>= 1) {
        z += __shfl_xor(z, off, 64);
        e += __shfl_xor(e, off, 64);
      }
      if (l16 == 0) {
        atomicAdd(&Zg[n], z);
        atomicAdd(&Eg[n], e);
      }
    }
  }
}

// ---------------------------------------------------------------------------
// k_x: X_h[n][d] = sum_k vn[n][h*64+k]*G[h][k][d] - zone correction.
// 256 thr = 4 waves = 4 heads; grid 400 = (200 row-tiles) x (2 head groups).
__global__ __launch_bounds__(256) void k_x(const unsigned short* __restrict__ vnfull,
                                           const float* __restrict__ Gf,
                                           const float* __restrict__ v,
                                           float* __restrict__ out) {
  __shared__ float Szone[16][4][12];
  int hl   = threadIdx.x >> 6;                  // local head 0..3
  int h    = ((int)blockIdx.x & 1) * 4 + hl;
  int lane = threadIdx.x & 63;
  int quad = lane >> 4, l16 = lane & 15;
  int n0 = (int)(blockIdx.x >> 1) * 16;
  int lo = (n0 / 10) * 10;
  int hi = ((n0 + 15) / 10) * 10 + 10;          // <= 3200, width <= 30

  // A-frags: rows n0..n0+15, dims h*64..h*64+63
  short8 aZ[2];
  #pragma unroll
  for (int kh = 0; kh < 2; kh++)
    aZ[kh] = *(const short8*)(vnfull + (size_t)(n0 + l16) * CC + h * DH + kh * 32 + quad * 8);

  // --- zone Gram S[n][m] for m in [lo, lo+32) ----------------------------
  #pragma unroll
  for (int ct = 0; ct < 2; ct++) {
    int rB = lo + ct * 16 + l16;
    int rC = rB < NN ? rB : NN - 1;              // clamp OOB (values unused)
    short8 b0 = *(const short8*)(vnfull + (size_t)rC * CC + h * DH + quad * 8);
    short8 b1 = *(const short8*)(vnfull + (size_t)rC * CC + h * DH + 32 + quad * 8);
    f32x4 c = (f32x4){0.f, 0.f, 0.f, 0.f};
    c = __builtin_amdgcn_mfma_f32_16x16x32_bf16(aZ[0], b0, c, 0, 0, 0);
    c = __builtin_amdgcn_mfma_f32_16x16x32_bf16(aZ[1], b1, c, 0, 0, 0);
    int m = lo + ct * 16 + l16;
    #pragma unroll
    for (int g = 0; g < 4; g++) {
      int n = n0 + quad * 4 + g;
      int bs = (n / 10) * 10;
      if (m >= bs && m < bs + 9 && m != n)
        Szone[quad * 4 + g][hl][m - bs] = c[g];
    }
  }

  // --- main term via G (read f32, pack bf16 in-reg) ----------------------
  f32x4 xr[4];
  #pragma unroll
  for (int nt = 0; nt < 4; nt++) {
    const float* gp = Gf + (size_t)h * 4096 + (nt * 16 + l16) * 64 + quad * 8;
    short8 g0 = pack8(*(const f32x4*)gp, *(const f32x4*)(gp + 4));
    short8 g1 = pack8(*(const f32x4*)(gp + 32), *(const f32x4*)(gp + 36));
    f32x4 c = (f32x4){0.f, 0.f, 0.f, 0.f};
    c = __builtin_amdgcn_mfma_f32_16x16x32_bf16(aZ[0], g0, c, 0, 0, 0);
    c = __builtin_amdgcn_mfma_f32_16x16x32_bf16(aZ[1], g1, c, 0, 0, 0);
    xr[nt] = c;
  }

  // --- correction: subtract zone contributions ---------------------------
  int bs_m = lo, moff = 0;
  for (int m = lo; m < hi; ++m, ++moff) {
    if (moff == 10) { moff = 0; bs_m += 10; }
    float vload[4];
    #pragma unroll
    for (int nt = 0; nt < 4; nt++)
      vload[nt] = v[(size_t)m * CC + h * DH + nt * 16 + l16];
    #pragma unroll
    for (int g = 0; g < 4; g++) {
      int n = n0 + quad * 4 + g;
      float s = 0.f;
      if (moff < 9 && n >= bs_m && n < bs_m + 10 && n != m)
        s = Szone[quad * 4 + g][hl][moff];
      #pragma unroll
      for (int nt = 0; nt < 4; nt++) xr[nt][g] -= s * vload[nt];
    }
  }

  // --- store -------------------------------------------------------------
  #pragma unroll
  for (int nt = 0; nt < 4; nt++)
    #pragma unroll
    for (int g = 0; g < 4; g++)
      out[(size_t)(n0 + quad * 4 + g) * (2 * CC) + h * DH + nt * 16 + l16] = xr[nt][g];
}

// ---------------------------------------------------------------------------
// k_soft: out2[n][m] = s>0 ? s / (Esel + EPS*Z) : 0   (s = signed-e)
__global__ void k_soft(const float* __restrict__ Rg, const float* __restrict__ Zg,
                       const float* __restrict__ Eg, float* __restrict__ out2) {
  unsigned int ui = (blockIdx.x * blockDim.x + threadIdx.x) * 4u;
  unsigned int n = ui / NN;
  f32x4 s4 = *(const f32x4*)(Rg + (size_t)ui);
  float rd = 1.0f / (Eg[n] + 1e-8f * Zg[n]);
  f32x4 o;
  #pragma unroll
  for (int j = 0; j < 4; j++) o[j] = (s4[j] > 0.f) ? s4[j] * rd : 0.f;
  *(f32x4*)(out2 + (size_t)ui) = o;
}

// ---------------------------------------------------------------------------
extern "C" void kernel_launch(void* const* d_in, const int* in_sizes, int n_in,
                              void* d_out, int out_size, void* d_ws, size_t ws_size,
                              hipStream_t stream) {
  const float* v = (const float*)d_in[1];   // only live input
  float* out = (float*)d_out;

  // ws carve: [Zg 3200][Eg 3200][Gf 32768] f32, [vnfull][vnT][vT] bf16, [Rg] f32
  float* Zg = (float*)d_ws;
  float* Eg = Zg + NN;
  float* Gf = Eg + NN;
  unsigned short* vnfull = (unsigned short*)(Gf + HEADS * DH * DH);
  unsigned short* vnT = vnfull + (size_t)NN * CC;
  unsigned short* vT  = vnT + (size_t)NN * CC;
  float* Rg = (float*)(vT + (size_t)NN * CC);

  hipMemsetAsync(d_ws, 0, (2 * NN + HEADS * DH * DH) * sizeof(float), stream);
  k_prep<<<dim3(HEADS * (NN / 64)), dim3(256), 0, stream>>>(v, vnfull, vnT, vT, out);
  k_gacc<<<dim3(HEADS * 10), dim3(256), 0, stream>>>(vT, vnT, Gf);
  k_rgemm<<<dim3(25 * 25), dim3(256), 0, stream>>>(vnfull, Rg, Zg, Eg);
  k_x<<<dim3((NN / 16) * 2), dim3(256), 0, stream>>>(vnfull, Gf, v, out);
  k_soft<<<dim3(NN * NN / 1024), dim3(256), 0, stream>>>(Rg, Zg, Eg, out + (size_t)NN * 2 * CC);
}

// Round 6
// 160.399 us; speedup vs baseline: 1.4056x; 1.1863x over previous
//
#include <hip/hip_runtime.h>
#include <math.h>

// Attention_msa_TwoStream. Only v_cls (d_in[1]) feeds outputs (MLP/q/k dead).
// N=3200, H=8, d=64, C=512; fp32 I/O; bf16 MFMA internals.
// R = (1/8) vnfull.vnfull^T is SYMMETRIC -> compute upper triangle tiles only.
// X_h = vn_h.(vn_h^T V_h) - block-zone correction (G_h is 64x64).

#define NN 3200
#define HEADS 8
#define DH 64
#define CC 512
#define TT 50                 // NN/64 tile rows
#define NTRI 1275             // TT*(TT+1)/2

typedef __attribute__((ext_vector_type(8))) short short8;   // 8 bf16
typedef __attribute__((ext_vector_type(4))) float f32x4;

static __device__ __forceinline__ unsigned short f2b(float f) {
  union { float f; unsigned u; } x; x.f = f;
  unsigned r = x.u + 0x7FFFu + ((x.u >> 16) & 1u);   // RTN-even
  return (unsigned short)(r >> 16);
}
static __device__ __forceinline__ float b2f(unsigned short s) {
  union { unsigned u; float f; } x; x.u = ((unsigned)s) << 16; return x.f;
}
static __device__ __forceinline__ short8 pack8(f32x4 lo, f32x4 hi) {
  short8 r;
  r[0] = (short)f2b(lo[0]); r[1] = (short)f2b(lo[1]);
  r[2] = (short)f2b(lo[2]); r[3] = (short)f2b(lo[3]);
  r[4] = (short)f2b(hi[0]); r[5] = (short)f2b(hi[1]);
  r[6] = (short)f2b(hi[2]); r[7] = (short)f2b(hi[3]);
  return r;
}

typedef const void __attribute__((address_space(1))) gvoid_t;
typedef void __attribute__((address_space(3))) lvoid_t;
static __device__ __forceinline__ void gl_lds16(const void* g, void* l) {
  __builtin_amdgcn_global_load_lds((gvoid_t*)g, (lvoid_t*)l, 16, 0, 0);
}

// ---------------------------------------------------------------------------
// k_prep: per-(n,h) L2 norm. Writes vnfull[n][512] bf16, vnT[h][k][n] bf16,
// vT[h][d][n] bf16 (raw V transposed), x_ori half of out (f32).
__global__ __launch_bounds__(256) void k_prep(const float* __restrict__ v,
                                              unsigned short* __restrict__ vnfull,
                                              unsigned short* __restrict__ vnT,
                                              unsigned short* __restrict__ vT,
                                              float* __restrict__ out) {
  __shared__ unsigned short tileV[DH][66];
  __shared__ unsigned short tileN[DH][66];
  int h  = blockIdx.x & 7;
  int n0 = (int)(blockIdx.x >> 3) * 64;
  int j  = threadIdx.x & 63;
  int r0 = threadIdx.x >> 6;       // 0..3
  #pragma unroll
  for (int i = 0; i < 16; i++) {
    int n = n0 + r0 * 16 + i;
    float val = v[(size_t)n * CC + h * DH + j];
    float ss = val * val;
    #pragma unroll
    for (int off = 32; off >= 1; off >>= 1) ss += __shfl_xor(ss, off, 64);
    float inv = 1.0f / (sqrtf(ss) + 1e-8f);
    unsigned short un = f2b(val * inv);
    tileV[j][r0 * 16 + i] = f2b(val);
    tileN[j][r0 * 16 + i] = un;
    vnfull[(size_t)n * CC + h * DH + j] = un;
    out[(size_t)n * (2 * CC) + CC + h * DH + j] = val;   // x_ori
  }
  __syncthreads();
  int r = threadIdx.x & 63;
  #pragma unroll
  for (int i = 0; i < 16; i++) {
    int jj = r0 * 16 + i;
    vT[((size_t)h * DH + jj) * NN + n0 + r]  = tileV[jj][r];
    vnT[((size_t)h * DH + jj) * NN + n0 + r] = tileN[jj][r];
  }
}

// ---------------------------------------------------------------------------
// k_gacc: Gf[h][d][k] += sum_m V[m][d]*vn[m][k]  (A=vT rows, B=vnT rows)
// grid 8 heads x 25 chunks (128 rows) = 200 blocks.
__global__ __launch_bounds__(256) void k_gacc(const unsigned short* __restrict__ vT,
                                              const unsigned short* __restrict__ vnT,
                                              float* __restrict__ Gf) {
  int h  = (int)blockIdx.x & 7;
  int ch = (int)blockIdx.x >> 3;
  int m0 = ch * 128;
  int w = threadIdx.x >> 6;
  int lane = threadIdx.x & 63;
  int quad = lane >> 4, l16 = lane & 15;
  f32x4 acc[4];
  #pragma unroll
  for (int ct = 0; ct < 4; ct++) acc[ct] = (f32x4){0.f, 0.f, 0.f, 0.f};
  const unsigned short* ap = vT + ((size_t)h * DH + w * 16 + l16) * NN + quad * 8;
  #pragma unroll
  for (int t = 0; t < 4; t++) {
    int mm = m0 + t * 32;
    short8 a = *(const short8*)(ap + mm);
    #pragma unroll
    for (int ct = 0; ct < 4; ct++) {
      short8 b = *(const short8*)(vnT + ((size_t)h * DH + ct * 16 + l16) * NN + mm + quad * 8);
      acc[ct] = __builtin_amdgcn_mfma_f32_16x16x32_bf16(a, b, acc[ct], 0, 0, 0);
    }
  }
  #pragma unroll
  for (int ct = 0; ct < 4; ct++)
    #pragma unroll
    for (int g = 0; g < 4; g++)
      atomicAdd(&Gf[(size_t)h * 4096 + (w * 16 + quad * 4 + g) * 64 + ct * 16 + l16],
                acc[ct][g]);
}

// ---------------------------------------------------------------------------
// k_rgemm: symmetric Gram, upper-triangle 64x64 tiles (1275 blocks).
// LDS double-buffered global_load_lds staging (BK=64), 4 waves of 32x32.
// Epilogue: one exp per element (exp(masked)=1); Rg bf16 = sel? e : -e,
// forward + mirrored stores; Z/E row atomics (rows forward, cols mirrored).
__global__ __launch_bounds__(256) void k_rgemm(const unsigned short* __restrict__ vnfull,
                                               unsigned short* __restrict__ Rg,
                                               float* __restrict__ Zg,
                                               float* __restrict__ Eg) {
  __shared__ __align__(16) unsigned short As[2][64 * 64];   // 16 KB
  __shared__ __align__(16) unsigned short Bs[2][64 * 64];   // 16 KB
  int p = (int)blockIdx.x;
  // triangle index: offset(a) = a*(101-a)/2
  int ti = (int)((101.0 - sqrt(10201.0 - 8.0 * (double)p)) * 0.5);
  while (ti * (101 - ti) / 2 > p) ti--;
  while ((ti + 1) * (100 - ti) / 2 <= p) ti++;
  int tj = ti + (p - ti * (101 - ti) / 2);
  int n0 = ti * 64, m0 = tj * 64;
  bool diag = (ti == tj);

  int tid = threadIdx.x;
  int wv = tid >> 6, wr = wv >> 1, wc = wv & 1;
  int lane = tid & 63, quad = lane >> 4, l16 = lane & 15;

  f32x4 acc[2][2];
  #pragma unroll
  for (int rt = 0; rt < 2; rt++)
    #pragma unroll
    for (int ct = 0; ct < 2; ct++) acc[rt][ct] = (f32x4){0.f, 0.f, 0.f, 0.f};

  // staging: chunk c covers (row=c>>3, 16B sub=c&7); LDS linear in c (required).
  int c0 = tid, c1 = tid + 256;
  int rowA0 = c0 >> 3, subA0 = c0 & 7, rowA1 = c1 >> 3, subA1 = c1 & 7;

  // prologue: stage buffer 0 (kw = 0)
  gl_lds16(vnfull + (size_t)(n0 + rowA0) * CC + subA0 * 8, &As[0][c0 * 8]);
  gl_lds16(vnfull + (size_t)(n0 + rowA1) * CC + subA1 * 8, &As[0][c1 * 8]);
  gl_lds16(vnfull + (size_t)(m0 + rowA0) * CC + subA0 * 8, &Bs[0][c0 * 8]);
  gl_lds16(vnfull + (size_t)(m0 + rowA1) * CC + subA1 * 8, &Bs[0][c1 * 8]);
  __syncthreads();

  #pragma unroll 1
  for (int kk = 0; kk < 8; kk++) {
    int buf = kk & 1;
    if (kk + 1 < 8) {
      int ko = (kk + 1) * 64;
      gl_lds16(vnfull + (size_t)(n0 + rowA0) * CC + ko + subA0 * 8, &As[buf ^ 1][c0 * 8]);
      gl_lds16(vnfull + (size_t)(n0 + rowA1) * CC + ko + subA1 * 8, &As[buf ^ 1][c1 * 8]);
      gl_lds16(vnfull + (size_t)(m0 + rowA0) * CC + ko + subA0 * 8, &Bs[buf ^ 1][c0 * 8]);
      gl_lds16(vnfull + (size_t)(m0 + rowA1) * CC + ko + subA1 * 8, &Bs[buf ^ 1][c1 * 8]);
    }
    short8 af[2][2], bf[2][2];
    #pragma unroll
    for (int rt = 0; rt < 2; rt++)
      #pragma unroll
      for (int kh = 0; kh < 2; kh++)
        af[rt][kh] = *(const short8*)&As[buf][(wr * 32 + rt * 16 + l16) * 64 + kh * 32 + quad * 8];
    #pragma unroll
    for (int ct = 0; ct < 2; ct++)
      #pragma unroll
      for (int kh = 0; kh < 2; kh++)
        bf[ct][kh] = *(const short8*)&Bs[buf][(wc * 32 + ct * 16 + l16) * 64 + kh * 32 + quad * 8];
    #pragma unroll
    for (int kh = 0; kh < 2; kh++)
      #pragma unroll
      for (int rt = 0; rt < 2; rt++)
        #pragma unroll
        for (int ct = 0; ct < 2; ct++)
          acc[rt][ct] = __builtin_amdgcn_mfma_f32_16x16x32_bf16(af[rt][kh], bf[ct][kh],
                                                                acc[rt][ct], 0, 0, 0);
    __syncthreads();
  }

  // ---- epilogue ----------------------------------------------------------
  int mloc[2], bs_col[2];
  #pragma unroll
  for (int ct = 0; ct < 2; ct++) {
    mloc[ct] = m0 + wc * 32 + ct * 16 + l16;
    bs_col[ct] = (mloc[ct] / 10) * 10;
  }
  float zcol[2] = {0.f, 0.f}, ecol[2] = {0.f, 0.f};

  #pragma unroll
  for (int rt = 0; rt < 2; rt++) {
    float zrow[4] = {0.f, 0.f, 0.f, 0.f}, erow[4] = {0.f, 0.f, 0.f, 0.f};
    unsigned long long mir[2] = {0ull, 0ull};
    #pragma unroll
    for (int g = 0; g < 4; g++) {
      int n = n0 + wr * 32 + rt * 16 + quad * 4 + g;
      int bs = (n / 10) * 10;
      #pragma unroll
      for (int ct = 0; ct < 2; ct++) {
        int m = mloc[ct];
        float R = acc[rt][ct][g] * 0.125f;
        float eR = __expf(R);
        bool sel = (R > 0.75f);
        bool zzf = (m >= bs) & (m < bs + 9) & (m != n);
        float ef = zzf ? 1.0f : eR;                    // exp(0)=1
        Rg[(size_t)n * NN + m] = f2b(sel ? ef : -ef);
        zrow[g] += ef;
        if (sel) erow[g] += ef;
        bool zzm = (n >= bs_col[ct]) & (n < bs_col[ct] + 9) & (n != m);
        float em = zzm ? 1.0f : eR;
        zcol[ct] += em;
        if (sel) ecol[ct] += em;
        mir[ct] |= (unsigned long long)f2b(sel ? em : -em) << (16 * g);
      }
    }
    if (!diag) {
      #pragma unroll
      for (int ct = 0; ct < 2; ct++)
        *(unsigned long long*)(Rg + (size_t)mloc[ct] * NN + n0 + wr * 32 + rt * 16 + quad * 4) =
            mir[ct];
    }
    #pragma unroll
    for (int g = 0; g < 4; g++) {
      float z = zrow[g], e = erow[g];
      #pragma unroll
      for (int off = 1; off <= 8; off <<= 1) {
        z += __shfl_xor(z, off, 64);
        e += __shfl_xor(e, off, 64);
      }
      if (l16 == 0) {
        int n = n0 + wr * 32 + rt * 16 + quad * 4 + g;
        atomicAdd(&Zg[n], z);
        atomicAdd(&Eg[n], e);
      }
    }
  }
  if (!diag) {
    #pragma unroll
    for (int ct = 0; ct < 2; ct++) {
      float z = zcol[ct], e = ecol[ct];
      z += __shfl_xor(z, 16, 64); z += __shfl_xor(z, 32, 64);
      e += __shfl_xor(e, 16, 64); e += __shfl_xor(e, 32, 64);
      if (quad == 0) {
        atomicAdd(&Zg[mloc[ct]], z);
        atomicAdd(&Eg[mloc[ct]], e);
      }
    }
  }
}

// ---------------------------------------------------------------------------
// k_x: X_h[n][d] = sum_k vn[n][h*64+k]*G[h][k][d] - zone correction (via MFMA:
// masked-negated zone-S round-trips LDS as bf16 A-frag, B = vT rows).
// 256 thr = 4 waves = 4 heads; grid 400 = 200 row-tiles x 2 head-groups.
__global__ __launch_bounds__(256) void k_x(const unsigned short* __restrict__ vnfull,
                                           const float* __restrict__ Gf,
                                           const unsigned short* __restrict__ vT,
                                           float* __restrict__ out) {
  __shared__ __align__(16) unsigned short Sz[4][16][48];
  int hl   = threadIdx.x >> 6;                  // local head
  int h    = ((int)blockIdx.x & 1) * 4 + hl;
  int lane = threadIdx.x & 63;
  int quad = lane >> 4, l16 = lane & 15;
  int n0 = (int)(blockIdx.x >> 1) * 16;
  int lo = (n0 / 10) * 10;                      // zone window [lo, lo+32)

  short8 aZ[2];
  #pragma unroll
  for (int kh = 0; kh < 2; kh++)
    aZ[kh] = *(const short8*)(vnfull + (size_t)(n0 + l16) * CC + h * DH + kh * 32 + quad * 8);

  // zone Gram -> masked negated bf16 into Sz[hl][row 0..15][col 0..31]
  #pragma unroll
  for (int ct = 0; ct < 2; ct++) {
    int rB = lo + ct * 16 + l16;
    int rC = rB < NN ? rB : NN - 1;             // clamp OOB (A side masks it)
    short8 b0 = *(const short8*)(vnfull + (size_t)rC * CC + h * DH + quad * 8);
    short8 b1 = *(const short8*)(vnfull + (size_t)rC * CC + h * DH + 32 + quad * 8);
    f32x4 cS = (f32x4){0.f, 0.f, 0.f, 0.f};
    cS = __builtin_amdgcn_mfma_f32_16x16x32_bf16(aZ[0], b0, cS, 0, 0, 0);
    cS = __builtin_amdgcn_mfma_f32_16x16x32_bf16(aZ[1], b1, cS, 0, 0, 0);
    int m = lo + ct * 16 + l16;
    #pragma unroll
    for (int g = 0; g < 4; g++) {
      int n = n0 + quad * 4 + g;
      int bs = (n / 10) * 10;
      bool keep = (m >= bs) & (m < bs + 9) & (m != n);
      Sz[hl][quad * 4 + g][ct * 16 + l16] = f2b(keep ? -cS[g] : 0.f);
    }
  }
  __syncthreads();

  // main term via G (f32 -> bf16 in-reg)
  f32x4 xr[4];
  #pragma unroll
  for (int nt = 0; nt < 4; nt++) {
    const float* gp = Gf + (size_t)h * 4096 + (nt * 16 + l16) * 64 + quad * 8;
    short8 g0 = pack8(*(const f32x4*)gp, *(const f32x4*)(gp + 4));
    short8 g1 = pack8(*(const f32x4*)(gp + 32), *(const f32x4*)(gp + 36));
    f32x4 cX = (f32x4){0.f, 0.f, 0.f, 0.f};
    cX = __builtin_amdgcn_mfma_f32_16x16x32_bf16(aZ[0], g0, cX, 0, 0, 0);
    cX = __builtin_amdgcn_mfma_f32_16x16x32_bf16(aZ[1], g1, cX, 0, 0, 0);
    xr[nt] = cX;
  }

  // correction: xr += (-Szone) . V[lo:lo+32)
  short8 aC = *(const short8*)&Sz[hl][l16][quad * 8];
  #pragma unroll
  for (int nt = 0; nt < 4; nt++) {
    short8 b = *(const short8*)(vT + (size_t)(h * DH + nt * 16 + l16) * NN + lo + quad * 8);
    xr[nt] = __builtin_amdgcn_mfma_f32_16x16x32_bf16(aC, b, xr[nt], 0, 0, 0);
  }

  #pragma unroll
  for (int nt = 0; nt < 4; nt++)
    #pragma unroll
    for (int g = 0; g < 4; g++)
      out[(size_t)(n0 + quad * 4 + g) * (2 * CC) + h * DH + nt * 16 + l16] = xr[nt][g];
}

// ---------------------------------------------------------------------------
// k_soft: out2[n][m] = s>0 ? s / (Esel + EPS*Z) : 0   (s = signed-e, bf16)
__global__ void k_soft(const unsigned short* __restrict__ Rg, const float* __restrict__ Zg,
                       const float* __restrict__ Eg, float* __restrict__ out2) {
  unsigned int base = (blockIdx.x * blockDim.x + threadIdx.x) * 8u;
  unsigned int n = base / NN;
  short8 s8 = *(const short8*)(Rg + (size_t)base);
  float rd = 1.0f / (Eg[n] + 1e-8f * Zg[n]);
  f32x4 o0, o1;
  #pragma unroll
  for (int j = 0; j < 4; j++) {
    float s = b2f((unsigned short)s8[j]);
    o0[j] = (s > 0.f) ? s * rd : 0.f;
    float t = b2f((unsigned short)s8[4 + j]);
    o1[j] = (t > 0.f) ? t * rd : 0.f;
  }
  *(f32x4*)(out2 + (size_t)base) = o0;
  *(f32x4*)(out2 + (size_t)base + 4) = o1;
}

// ---------------------------------------------------------------------------
extern "C" void kernel_launch(void* const* d_in, const int* in_sizes, int n_in,
                              void* d_out, int out_size, void* d_ws, size_t ws_size,
                              hipStream_t stream) {
  const float* v = (const float*)d_in[1];   // only live input
  float* out = (float*)d_out;

  // ws carve (~30.5 MB): [Zg][Eg][Gf] f32, [vnfull][vnT][vT] bf16, [Rg] bf16
  float* Zg = (float*)d_ws;
  float* Eg = Zg + NN;
  float* Gf = Eg + NN;
  unsigned short* vnfull = (unsigned short*)(Gf + HEADS * DH * DH);
  unsigned short* vnT = vnfull + (size_t)NN * CC;
  unsigned short* vT  = vnT + (size_t)NN * CC;
  unsigned short* Rg  = vT + (size_t)NN * CC;

  hipMemsetAsync(d_ws, 0, (2 * NN + HEADS * DH * DH) * sizeof(float), stream);
  k_prep<<<dim3(HEADS * (NN / 64)), dim3(256), 0, stream>>>(v, vnfull, vnT, vT, out);
  k_gacc<<<dim3(HEADS * 25), dim3(256), 0, stream>>>(vT, vnT, Gf);
  k_rgemm<<<dim3(NTRI), dim3(256), 0, stream>>>(vnfull, Rg, Zg, Eg);
  k_x<<<dim3((NN / 16) * 2), dim3(256), 0, stream>>>(vnfull, Gf, vT, out);
  k_soft<<<dim3(NN * NN / 2048), dim3(256), 0, stream>>>(Rg, Zg, Eg, out + (size_t)NN * 2 * CC);
}